// Round 6
// baseline (417.565 us; speedup 1.0000x reference)
//
#include <hip/hip_runtime.h>

// Round 13: r12 transposed kernel + ONE-LINE prefetch fix.
// r12's failure (absmax 0.033) was NOT the transposed layout: the single
// xpv prefetch register kept r9's dual-register refill distance (t+4), so
// odd steps staged x(t+3)'s slot with x(t+4) -> wrong x for half the
// timesteps. Fix: refill with x(t+3) (consumed at step t+1's staging
// point: ~1.2 steps of slack, rides the barrier on vmcnt).
//
// Design (unchanged from r12): gates^T = W * [x;h]^T. M = gate-cols (512,
// A-operand = weights in regs), N = batch (16, B-operand = data in LDS),
// K = 128/64. N-cols of MFMA are independent -> no dup writes needed
// (cols 8-15 = ignored garbage, finite by zero-init + |h|<1). 4 waves x
// 8 M-tiles:
//  - LDS reads/CU/step: 48 -> 24 ds_read_b128 (the modeled LDS-pipe
//    serialization burst halves)
//  - h-write: 4 cells/lane at consecutive hcols -> ONE ds_write_b64 per
//    hb (8 write instrs/CU/step), fully static acc indexing
//  - staging: 256 thr x 1 uint, no dup
// Same per-CU MFMA count as r9. VGPR ~300 -> 1 wave/SIMD; fine: waves are
// barrier-locked anyway; 8 indep MFMA chains + 8 indep cells give ILP.
// Kept from r8/r9: non-draining lgkmcnt-only barrier, prescaled weights
// (exp2 direct), rcp-fused cells, coalesced x prefetch.

#define Bsz   2048
#define Tlen  256
#define Fdim  64
#define Hdim  128
#define ROWS  8
#define NTH   256
#define TILE_E 512            // elems per kt tile (64 lanes x 8)
#define NKT   6               // kt 0,1 = x (K 0..63); kt 2..5 = h (K 0..127)
#define BUF_E (NKT * TILE_E)  // 3072 bf16 = 6 KB per buffer

using bf16x8 = __attribute__((ext_vector_type(8))) __bf16;
using bf16x4 = __attribute__((ext_vector_type(4))) __bf16;
using f32x4  = __attribute__((ext_vector_type(4))) float;

__device__ __forceinline__ float fast_rcp(float x) {
#if __has_builtin(__builtin_amdgcn_rcpf)
    return __builtin_amdgcn_rcpf(x);
#else
    return 1.0f / x;
#endif
}
__device__ __forceinline__ float fast_exp2(float x) {
#if __has_builtin(__builtin_amdgcn_exp2f)
    return __builtin_amdgcn_exp2f(x);
#else
    return exp2f(x);
#endif
}
#define LOG2E  1.4426950408889634f
#define LOG2E2 2.8853900817779268f

__device__ __forceinline__ bf16x8 cvt8s(float4 a, float4 b, float s) {
    bf16x8 r;
    r[0]=(__bf16)(s*a.x); r[1]=(__bf16)(s*a.y); r[2]=(__bf16)(s*a.z); r[3]=(__bf16)(s*a.w);
    r[4]=(__bf16)(s*b.x); r[5]=(__bf16)(s*b.y); r[6]=(__bf16)(s*b.z); r[7]=(__bf16)(s*b.w);
    return r;
}

__global__ __launch_bounds__(NTH, 1)
void lstm_fused(const float* __restrict__ x,
                const float* __restrict__ W_ih,
                const float* __restrict__ W_hh,
                const float* __restrict__ b_ih,
                const float* __restrict__ b_hh,
                const float* __restrict__ W1,
                const float* __restrict__ b1,
                const float* __restrict__ W2,
                const float* __restrict__ b2,
                float* __restrict__ out)
{
    __shared__ __bf16 Abuf[2][BUF_E];       // B-operand tiles: [k][n] frag order
    __shared__ float  hlast[ROWS * Hdim];   // 4 KB fp32 h_T for head
    __shared__ float  zbuf[ROWS * 32];

    const int tid  = threadIdx.x;
    const int w    = tid >> 6;              // wave 0..3
    const int lane = tid & 63;
    const int q    = lane >> 4;
    const int l16  = lane & 15;
    const int b0   = blockIdx.x * ROWS;

    // ---- weights as A-frags, register-resident, prescaled ----
    // tile (hb,j): gate-cols gb = j*128 + (2w+hb)*16 + (0..15)
    // A-frag lane (q,l16): A[row=l16][k = kt*32 + q*8 + jj]
    bf16x8 bwh[2][4][4];   // [hb][j][kt]  h-part K=128
    bf16x8 bwx[2][4][2];   // [hb][j][kt]  x-part K=64
    f32x4  biasf[2][4];    // bias along M: elem e -> gate-col gb + 4q + e
    #pragma unroll
    for (int hb = 0; hb < 2; ++hb) {
        #pragma unroll
        for (int j = 0; j < 4; ++j) {
            const float s  = (j == 2) ? -LOG2E2 : -LOG2E;
            const int   gb = j * Hdim + (2 * w + hb) * 16;
            const float* ph = W_hh + (size_t)(gb + l16) * Hdim;
            #pragma unroll
            for (int kt = 0; kt < 4; ++kt) {
                float4 lo = *(const float4*)(ph + kt * 32 + q * 8);
                float4 hi = *(const float4*)(ph + kt * 32 + q * 8 + 4);
                bwh[hb][j][kt] = cvt8s(lo, hi, s);
            }
            const float* px = W_ih + (size_t)(gb + l16) * Fdim;
            #pragma unroll
            for (int kt = 0; kt < 2; ++kt) {
                float4 lo = *(const float4*)(px + kt * 32 + q * 8);
                float4 hi = *(const float4*)(px + kt * 32 + q * 8 + 4);
                bwx[hb][j][kt] = cvt8s(lo, hi, s);
            }
            const int be = gb + 4 * q;
            float4 bi = *(const float4*)(b_ih + be);
            float4 bh = *(const float4*)(b_hh + be);
            biasf[hb][j] = (f32x4){s*(bi.x+bh.x), s*(bi.y+bh.y),
                                   s*(bi.z+bh.z), s*(bi.w+bh.w)};
        }
    }

    // ---- x staging: 256 threads, 1 uint write/step (n = batch 0..7) ----
    const int  sb  = tid & 7;               // batch row
    const int  f0  = 2 * ((tid >> 3) & 31); // feature pair
    const float* xrp = x + (size_t)(b0 + sb) * (Tlen * Fdim) + f0;
    const int  sx_e = (f0 >> 5) * TILE_E + (((f0 >> 3) & 3) * 16 + sb) * 8 + (f0 & 7);

    // ---- cell geometry: lane (q,l16) -> batch=l16 (l16>=8 garbage),
    //      hcols kh0[hb] + e, kh0 = (2w+hb)*16 + 4q ----
    const int kh0_0 = (2 * w + 0) * 16 + 4 * q;
    const int kh0_1 = (2 * w + 1) * 16 + 4 * q;
    const int wr_e0 = (2 + (kh0_0 >> 5)) * TILE_E + (((kh0_0 >> 3) & 3) * 16 + l16) * 8 + (kh0_0 & 7);
    const int wr_e1 = (2 + (kh0_1 >> 5)) * TILE_E + (((kh0_1 >> 3) & 3) * 16 + l16) * 8 + (kh0_1 & 7);

    // ---- init: zero BOTH buffers (h(-1)=0; x n=8..15 stay 0 forever) ----
    #pragma unroll
    for (int i = 0; i < 2 * BUF_E / NTH; ++i)
        ((__bf16*)Abuf)[tid + i * NTH] = (__bf16)0.0f;
    __syncthreads();
    // stage x(0) -> Abuf[1].x, x(1) -> Abuf[0].x
    {
        float2 v0 = *(const float2*)(xrp);
        float2 v1 = *(const float2*)(xrp + Fdim);
        __bf16 a0[2] = {(__bf16)v0.x, (__bf16)v0.y};
        __bf16 a1[2] = {(__bf16)v1.x, (__bf16)v1.y};
        *(uint*)&Abuf[1][sx_e] = *(uint*)a0;
        *(uint*)&Abuf[0][sx_e] = *(uint*)a1;
    }
    float2 xpv = *(const float2*)(xrp + 2 * Fdim);   // x(2), staged at t=0
    __syncthreads();
    // prologue x-GEMM: xacc = xpart(0) from Abuf[1] x-slots
    f32x4 xacc[2][4];
    {
        bf16x8 xf0 = *(const bf16x8*)&Abuf[1][lane * 8];
        bf16x8 xf1 = *(const bf16x8*)&Abuf[1][TILE_E + lane * 8];
        #pragma unroll
        for (int hb = 0; hb < 2; ++hb)
            #pragma unroll
            for (int j = 0; j < 4; ++j) {
                f32x4 tmp = __builtin_amdgcn_mfma_f32_16x16x32_bf16(bwx[hb][j][0], xf0, biasf[hb][j], 0, 0, 0);
                xacc[hb][j] = __builtin_amdgcn_mfma_f32_16x16x32_bf16(bwx[hb][j][1], xf1, tmp, 0, 0, 0);
            }
    }
    __syncthreads();   // protect Abuf[1].x until all waves' reads done

    float cc[2][4];
    #pragma unroll
    for (int hb = 0; hb < 2; ++hb)
        #pragma unroll
        for (int e = 0; e < 4; ++e) cc[hb][e] = 0.0f;

    // One step: [6x ds_read | xcur=xpv; prefetch x(t+3) | 32 h-MFMA |
    // 16 x-MFMA | staging write x(t+2) | SB(0) | 8 cells (static idx) |
    // 2x ds_write_b64 | lgkmcnt | s_barrier]
    auto step = [&](int t, const __bf16* __restrict__ rb,
                    __bf16* __restrict__ wbf) {
        bf16x8 hf[4];
        #pragma unroll
        for (int kt = 0; kt < 4; ++kt)
            hf[kt] = *(const bf16x8*)&rb[(2 + kt) * TILE_E + lane * 8];
        bf16x8 xf0 = *(const bf16x8*)&rb[lane * 8];
        bf16x8 xf1 = *(const bf16x8*)&rb[TILE_E + lane * 8];

        float2 xcur = xpv;
        // FIX (was t+4): single prefetch register is consumed every step at
        // the staging point of step t+1, so refill distance is t+3.
        if ((t + 3) < Tlen)
            xpv = *(const float2*)(xrp + (size_t)(t + 3) * Fdim);

        // gates^T(t): C-in = xacc; 32 MFMAs, 8 independent depth-4 chains
        f32x4 acc[2][4];
        #pragma unroll
        for (int hb = 0; hb < 2; ++hb)
            #pragma unroll
            for (int j = 0; j < 4; ++j)
                acc[hb][j] = __builtin_amdgcn_mfma_f32_16x16x32_bf16(bwh[hb][j][0], hf[0], xacc[hb][j], 0, 0, 0);
        #pragma unroll
        for (int kt = 1; kt < 4; ++kt)
            #pragma unroll
            for (int hb = 0; hb < 2; ++hb)
                #pragma unroll
                for (int j = 0; j < 4; ++j)
                    acc[hb][j] = __builtin_amdgcn_mfma_f32_16x16x32_bf16(bwh[hb][j][kt], hf[kt], acc[hb][j], 0, 0, 0);

        // xacc(t+1) = bias + x(t+1)W_ih^T -- drains under elementwise
        if ((t + 1) < Tlen) {
            #pragma unroll
            for (int hb = 0; hb < 2; ++hb)
                #pragma unroll
                for (int j = 0; j < 4; ++j) {
                    f32x4 tmp = __builtin_amdgcn_mfma_f32_16x16x32_bf16(bwx[hb][j][0], xf0, biasf[hb][j], 0, 0, 0);
                    xacc[hb][j] = __builtin_amdgcn_mfma_f32_16x16x32_bf16(bwx[hb][j][1], xf1, tmp, 0, 0, 0);
                }
        }

        // stage x(t+2) (held in xcur), n = batch 0..7 only
        if ((t + 2) < Tlen) {
            __bf16 xa[2] = {(__bf16)xcur.x, (__bf16)xcur.y};
            *(uint*)&wbf[sx_e] = *(uint*)xa;
        }

        __builtin_amdgcn_sched_barrier(0);

        // 8 cells, fully static acc indexing; 4 h's pack into one b64/hb
        #pragma unroll
        for (int hb = 0; hb < 2; ++hb) {
            bf16x4 hv;
            float  hl[4];
            #pragma unroll
            for (int e = 0; e < 4; ++e) {
                float ei = fast_exp2(acc[hb][0][e]);
                float ef = fast_exp2(acc[hb][1][e]);
                float eg = fast_exp2(acc[hb][2][e]);
                float eo = fast_exp2(acc[hb][3][e]);
                float a = 1.0f + ef, b = 1.0f + ei, d = 1.0f + eg;
                float bd  = b * d;
                float num = cc[hb][e] * bd + a * (1.0f - eg);
                float c   = num * fast_rcp(a * bd);
                cc[hb][e] = c;
                float ec = fast_exp2(-LOG2E2 * c);
                float h  = (1.0f - ec) * fast_rcp((1.0f + eo) * (1.0f + ec));
                hv[e] = (__bf16)h;
                hl[e] = h;
            }
            *(bf16x4*)&wbf[hb ? wr_e1 : wr_e0] = hv;
            if (t == Tlen - 1 && l16 < 8) {
                *(float4*)&hlast[l16 * Hdim + (hb ? kh0_1 : kh0_0)] =
                    make_float4(hl[0], hl[1], hl[2], hl[3]);
            }
        }

        // non-draining barrier: LDS visible; x prefetch rides on vmcnt
        asm volatile("s_waitcnt lgkmcnt(0)" ::: "memory");
        __builtin_amdgcn_s_barrier();
        __builtin_amdgcn_sched_barrier(0);
    };

    for (int t = 0; t < Tlen; t += 2) {
        step(t,     Abuf[0], Abuf[1]);
        step(t + 1, Abuf[1], Abuf[0]);
    }

    // ---- head: z = relu(h @ W1^T + b1); out = sigmoid(z @ W2^T + b2) ----
    // (final loop barrier synced all waves: hlast safe)
    {
        const int b = tid >> 5, n = tid & 31;   // 256 threads = 8 x 32
        const float4* w4 = (const float4*)(W1 + n * Hdim);
        const float4* h4 = (const float4*)(hlast + b * Hdim);
        float s = b1[n];
        #pragma unroll
        for (int kk = 0; kk < Hdim / 4; ++kk) {
            float4 wv = w4[kk];
            float4 hv = h4[kk];
            s += wv.x * hv.x + wv.y * hv.y + wv.z * hv.z + wv.w * hv.w;
        }
        zbuf[b * 32 + n] = fmaxf(s, 0.0f);
    }
    __syncthreads();
    if (tid < ROWS) {
        float s = b2[0];
        #pragma unroll
        for (int n = 0; n < 32; ++n) s += zbuf[tid * 32 + n] * W2[n];
        float e = fast_exp2(-LOG2E * s);
        out[b0 + tid] = fast_rcp(1.0f + e);
    }
}

extern "C" void kernel_launch(void* const* d_in, const int* in_sizes, int n_in,
                              void* d_out, int out_size, void* d_ws, size_t ws_size,
                              hipStream_t stream) {
    const float* x    = (const float*)d_in[0];
    const float* W_ih = (const float*)d_in[1];
    const float* W_hh = (const float*)d_in[2];
    const float* b_ih = (const float*)d_in[3];
    const float* b_hh = (const float*)d_in[4];
    const float* W1   = (const float*)d_in[5];
    const float* b1   = (const float*)d_in[6];
    const float* W2   = (const float*)d_in[7];
    const float* b2   = (const float*)d_in[8];
    float* out = (float*)d_out;

    dim3 grid(Bsz / ROWS), block(NTH);
    lstm_fused<<<grid, block, 0, stream>>>(x, W_ih, W_hh, b_ih, b_hh, W1, b1, W2, b2, out);
}

// Round 7
// 398.119 us; speedup vs baseline: 1.0488x; 1.0488x over previous
//
#include <hip/hip_runtime.h>

// Round 14: r9 (223us, best) restructured into a TWO-PHASE step (T3-style).
// All-rounds model: step ~2095 cyc = elementwise VALU 600/SIMD (invariant)
// + MFMA 233/SIMD + LDS ~880/CU + ~600-900 exposure (dep chains + barrier
// convergence). Only exposure-attacks ever won (r8). So: split h-GEMM K
// into lo (hcols 0-63, waves 0-3) and hi (hcols 64-127, waves 4-7):
//   Window A (..->B1): read h-hi(t-1)+x frags, finish acc(t) [8 MFMA],
//     xacc(t+1) [8 MFMA]; hi-waves stage x; LO-waves cellmath + write h-lo.
//   Window B (B1->B2): read h-lo(t), partial acc(t+1) [8 MFMA onto xacc];
//     HI-waves cellmath + write h-hi.
// Each SIMD = 1 lo-wave + 1 hi-wave (w%4): per-window critical VALU halves
// and overlaps the other group's reads+MFMAs; the LDS burst splits 32/16;
// next step's lo-reads hide under hi-elementwise. Layout/math identical to
// r9 (dup-8 M=16 tile, reg-resident weights, rcp-fused cells, lgkmcnt-only
// barriers, dual 2-step-slack x prefetch; staging moved to waves 4-7).

#define Bsz   2048
#define Tlen  256
#define Fdim  64
#define Hdim  128
#define ROWS  8
#define NTH   512
#define TILE_E 512            // elems per kt tile (64 lanes x 8)
#define NKT   6               // kt 0,1 = x (K 0..63), kt 2..5 = h (K 64..191)
#define BUF_E (NKT * TILE_E)  // 3072 bf16 = 6 KB per buffer

using bf16x8 = __attribute__((ext_vector_type(8))) __bf16;
using f32x4  = __attribute__((ext_vector_type(4))) float;

__device__ __forceinline__ float fast_rcp(float x) {
#if __has_builtin(__builtin_amdgcn_rcpf)
    return __builtin_amdgcn_rcpf(x);
#else
    return 1.0f / x;
#endif
}
__device__ __forceinline__ float fast_exp2(float x) {
#if __has_builtin(__builtin_amdgcn_exp2f)
    return __builtin_amdgcn_exp2f(x);
#else
    return exp2f(x);
#endif
}
#define LOG2E  1.4426950408889634f
#define LOG2E2 2.8853900817779268f

__device__ __forceinline__ bf16x8 cvt8(float4 a, float4 b) {
    bf16x8 r;
    r[0]=(__bf16)a.x; r[1]=(__bf16)a.y; r[2]=(__bf16)a.z; r[3]=(__bf16)a.w;
    r[4]=(__bf16)b.x; r[5]=(__bf16)b.y; r[6]=(__bf16)b.z; r[7]=(__bf16)b.w;
    return r;
}

// frag-order elem index for logical A[frag_row][k]
__device__ __forceinline__ int frag_elem(int row, int k) {
    return (k >> 5) * TILE_E + ((((k >> 3) & 3) * 16 + row) * 8) + (k & 7);
}

__global__ __launch_bounds__(NTH, 2)
void lstm_fused(const float* __restrict__ x,
                const float* __restrict__ W_ih,
                const float* __restrict__ W_hh,
                const float* __restrict__ b_ih,
                const float* __restrict__ b_hh,
                const float* __restrict__ W1,
                const float* __restrict__ b1,
                const float* __restrict__ W2,
                const float* __restrict__ b2,
                float* __restrict__ out)
{
    __shared__ __bf16 Abuf[2][BUF_E];       // 12 KB, fragment-order A operand
    __shared__ float  hlast[ROWS * Hdim];   // 4 KB fp32 h_T for head
    __shared__ float  zbuf[ROWS * 32];

    const int tid  = threadIdx.x;
    const int w    = tid >> 6;
    const int lane = tid & 63;
    const int quad = lane >> 4;
    const int l16  = lane & 15;
    const int b0   = blockIdx.x * ROWS;
    const bool hiq  = (quad >= 2);          // acc elems {2,3} vs {0,1}
    const bool loW  = (w < 4);              // lo-waves own hcols 0..63

    // ---- weights, register-resident (bf16x8 = 4 VGPR; 24 frags = 96) ----
    // lane holds B[k = kt*32 + quad*8 + j][n = g*128 + w*16 + l16]
    bf16x8 bwx[2][4], bwh[4][4];
    #pragma unroll
    for (int kt = 0; kt < NKT; ++kt) {
        const int k0 = kt * 32 + quad * 8;
        #pragma unroll
        for (int g = 0; g < 4; ++g) {
            const int n = g * Hdim + w * 16 + l16;
            const float* p = (kt < 2) ? (W_ih + (size_t)n * Fdim + k0)
                                      : (W_hh + (size_t)n * Hdim + (k0 - Fdim));
            float4 lo = *(const float4*)p;
            float4 hi = *(const float4*)(p + 4);
            bf16x8 r = cvt8(lo, hi);
            if (kt < 2) bwx[kt][g] = r; else bwh[kt - 2][g] = r;
        }
    }
    f32x4 biasf[4];
    #pragma unroll
    for (int g = 0; g < 4; ++g) {
        const int n = g * Hdim + w * 16 + l16;
        const float bv = b_ih[n] + b_hh[n];
        biasf[g] = (f32x4){bv, bv, bv, bv};
    }

    // ---- x staging: waves 4-7 (256 threads), dup-on-write both rows ----
    const bool sx_on  = tid >= 256;
    const int  tix    = tid & 255;
    const int  sx_row = tix & 7;
    const int  f0     = 2 * ((tix >> 3) & 31);
    const float* xrp  = x + (size_t)(b0 + sx_row) * (Tlen * Fdim) + f0;
    const int sx_e0 = frag_elem(sx_row,     f0);
    const int sx_e1 = frag_elem(sx_row + 8, f0);

    // ---- elementwise cells (r5 mapping): 2 real cells/lane ----
    const int r0  = (quad >> 1) * 2;
    const int brb = (quad & 1) * 4 + r0;     // batch rows brb, brb+1
    const int hc  = 16 * w + l16;            // H-col; w<4 => hc<64 (lo half)
    const int h_e0a = frag_elem(brb,         Fdim + hc);
    const int h_e0b = frag_elem(brb + 8,     Fdim + hc);
    const int h_e1a = frag_elem(brb + 1,     Fdim + hc);
    const int h_e1b = frag_elem(brb + 1 + 8, Fdim + hc);

    // ---- init: zero buf0 (h(-1)=0), stage x(1)->buf0, prefetch x(2),x(3) ----
    #pragma unroll
    for (int i = 0; i < BUF_E / NTH; ++i)
        Abuf[0][tid + i * NTH] = (__bf16)0.0f;
    __syncthreads();
    float2 xpA = make_float2(0.f, 0.f);      // staged at even t
    float2 xpB = make_float2(0.f, 0.f);      // staged at odd  t
    if (sx_on) {
        float2 v1 = *(const float2*)(xrp + Fdim);     // x(1) -> buf0 x-slots
        __bf16 a1[2] = {(__bf16)v1.x, (__bf16)v1.y};
        *(uint*)&Abuf[0][sx_e0] = *(uint*)a1;
        *(uint*)&Abuf[0][sx_e1] = *(uint*)a1;
        xpA = *(const float2*)(xrp + 2 * Fdim);       // x(2), staged at t=0
        xpB = *(const float2*)(xrp + 3 * Fdim);       // x(3), staged at t=1
    }
    // pacc(0) = bias + x(0) W_ih^T (h-lo(-1)=0 so kt23 contribution is 0)
    f32x4 pacc[4];
    {
        const float* x0p = x + (size_t)(b0 + (l16 & 7)) * (Tlen * Fdim) + quad * 8;
        float4 a0 = *(const float4*)(x0p);
        float4 a1 = *(const float4*)(x0p + 4);
        float4 a2 = *(const float4*)(x0p + 32);
        float4 a3 = *(const float4*)(x0p + 36);
        bf16x8 xi0 = cvt8(a0, a1), xi1 = cvt8(a2, a3);
        #pragma unroll
        for (int g = 0; g < 4; ++g) {
            f32x4 tmp = __builtin_amdgcn_mfma_f32_16x16x32_bf16(xi0, bwx[0][g], biasf[g], 0, 0, 0);
            pacc[g]   = __builtin_amdgcn_mfma_f32_16x16x32_bf16(xi1, bwx[1][g], tmp, 0, 0, 0);
        }
    }
    __syncthreads();

    float cc0 = 0.0f, cc1 = 0.0f;
    f32x4 acc[4];     // completed gates(t), lives window A -> window B
    f32x4 xaccN[4];   // bias + x(t+1)W_ih^T, lives window A -> window B

    // r9's proven cell math (rcp-fused); writes h into wbf + hlast at end.
    auto cellmath = [&](int t, __bf16* __restrict__ wbf) {
        {
            float gi = hiq ? acc[0][2] : acc[0][0];
            float gf = hiq ? acc[1][2] : acc[1][0];
            float gg = hiq ? acc[2][2] : acc[2][0];
            float go = hiq ? acc[3][2] : acc[3][0];
            float ei = fast_exp2(-LOG2E  * gi);
            float ef = fast_exp2(-LOG2E  * gf);
            float eg = fast_exp2(-LOG2E2 * gg);
            float eo = fast_exp2(-LOG2E  * go);
            float a = 1.0f + ef, b = 1.0f + ei, d = 1.0f + eg;
            float bd  = b * d;
            float num = cc0 * bd + a * (1.0f - eg);
            cc0 = num * fast_rcp(a * bd);
            float ec = fast_exp2(-LOG2E2 * cc0);
            float h  = (1.0f - ec) * fast_rcp((1.0f + eo) * (1.0f + ec));
            __bf16 hb = (__bf16)h;
            wbf[h_e0a] = hb;
            wbf[h_e0b] = hb;
            if (t == Tlen - 1) hlast[brb * Hdim + hc] = h;
        }
        {
            float gi = hiq ? acc[0][3] : acc[0][1];
            float gf = hiq ? acc[1][3] : acc[1][1];
            float gg = hiq ? acc[2][3] : acc[2][1];
            float go = hiq ? acc[3][3] : acc[3][1];
            float ei = fast_exp2(-LOG2E  * gi);
            float ef = fast_exp2(-LOG2E  * gf);
            float eg = fast_exp2(-LOG2E2 * gg);
            float eo = fast_exp2(-LOG2E  * go);
            float a = 1.0f + ef, b = 1.0f + ei, d = 1.0f + eg;
            float bd  = b * d;
            float num = cc1 * bd + a * (1.0f - eg);
            cc1 = num * fast_rcp(a * bd);
            float ec = fast_exp2(-LOG2E2 * cc1);
            float h  = (1.0f - ec) * fast_rcp((1.0f + eo) * (1.0f + ec));
            __bf16 hb = (__bf16)h;
            wbf[h_e1a] = hb;
            wbf[h_e1b] = hb;
            if (t == Tlen - 1) hlast[(brb + 1) * Hdim + hc] = h;
        }
    };

    // WINDOW A (B2(t-1) -> B1(t)): finish acc(t) with h-hi(t-1) [tiles 4,5
    // of rb], compute xacc(t+1) from x(t+1) [tiles 0,1 of rb]; hi-waves
    // stage x(t+2) into wbf; lo-waves cellmath + write h-lo(t) into wbf.
    auto windowA = [&](int t, const __bf16* __restrict__ rb,
                       __bf16* __restrict__ wbf, float2& xstage) {
        bf16x8 hf2 = *(const bf16x8*)&rb[(2 + 2) * TILE_E + lane * 8];
        bf16x8 hf3 = *(const bf16x8*)&rb[(2 + 3) * TILE_E + lane * 8];
        bf16x8 xf0 = *(const bf16x8*)&rb[lane * 8];
        bf16x8 xf1 = *(const bf16x8*)&rb[TILE_E + lane * 8];

        float2 xcur = xstage;
        if (sx_on && (t + 4) < Tlen)
            xstage = *(const float2*)(xrp + (size_t)(t + 4) * Fdim);

        #pragma unroll
        for (int g = 0; g < 4; ++g)
            acc[g] = __builtin_amdgcn_mfma_f32_16x16x32_bf16(hf2, bwh[2][g], pacc[g], 0, 0, 0);
        #pragma unroll
        for (int g = 0; g < 4; ++g)
            acc[g] = __builtin_amdgcn_mfma_f32_16x16x32_bf16(hf3, bwh[3][g], acc[g], 0, 0, 0);

        if ((t + 1) < Tlen) {
            #pragma unroll
            for (int g = 0; g < 4; ++g) {
                f32x4 tmp = __builtin_amdgcn_mfma_f32_16x16x32_bf16(xf0, bwx[0][g], biasf[g], 0, 0, 0);
                xaccN[g]  = __builtin_amdgcn_mfma_f32_16x16x32_bf16(xf1, bwx[1][g], tmp, 0, 0, 0);
            }
        }

        if (sx_on && (t + 2) < Tlen) {
            __bf16 xa[2] = {(__bf16)xcur.x, (__bf16)xcur.y};
            *(uint*)&wbf[sx_e0] = *(uint*)xa;
            *(uint*)&wbf[sx_e1] = *(uint*)xa;
        }

        __builtin_amdgcn_sched_barrier(0);
        if (loW) cellmath(t, wbf);           // writes h-lo(t), tiles 2,3

        asm volatile("s_waitcnt lgkmcnt(0)" ::: "memory");
        __builtin_amdgcn_s_barrier();        // B1(t): h-lo(t) + staged x vis
        __builtin_amdgcn_sched_barrier(0);
    };

    // WINDOW B (B1(t) -> B2(t)): partial acc(t+1) = xaccN + kt23 with
    // h-lo(t) [tiles 2,3 of wbf]; hi-waves cellmath + write h-hi(t).
    auto windowB = [&](int t, __bf16* __restrict__ wbf) {
        if ((t + 1) < Tlen) {
            bf16x8 hf0 = *(const bf16x8*)&wbf[(2 + 0) * TILE_E + lane * 8];
            bf16x8 hf1 = *(const bf16x8*)&wbf[(2 + 1) * TILE_E + lane * 8];
            #pragma unroll
            for (int g = 0; g < 4; ++g) {
                f32x4 tmp = __builtin_amdgcn_mfma_f32_16x16x32_bf16(hf0, bwh[0][g], xaccN[g], 0, 0, 0);
                pacc[g]   = __builtin_amdgcn_mfma_f32_16x16x32_bf16(hf1, bwh[1][g], tmp, 0, 0, 0);
            }
        }

        __builtin_amdgcn_sched_barrier(0);
        if (!loW) cellmath(t, wbf);          // writes h-hi(t), tiles 4,5

        asm volatile("s_waitcnt lgkmcnt(0)" ::: "memory");
        __builtin_amdgcn_s_barrier();        // B2(t): h-hi(t) visible
        __builtin_amdgcn_sched_barrier(0);
    };

    for (int t = 0; t < Tlen; t += 2) {
        windowA(t,     Abuf[0], Abuf[1], xpA);
        windowB(t,     Abuf[1]);
        windowA(t + 1, Abuf[1], Abuf[0], xpB);
        windowB(t + 1, Abuf[0]);
    }

    // ---- head: z = relu(h @ W1^T + b1); out = sigmoid(z @ W2^T + b2) ----
    // (loop's final B2 synced all waves + drained lgkm: hlast safe)
    if (tid < ROWS * 32) {
        const int b = tid >> 5, n = tid & 31;
        const float4* w4 = (const float4*)(W1 + n * Hdim);
        const float4* h4 = (const float4*)(hlast + b * Hdim);
        float s = b1[n];
        #pragma unroll
        for (int kk = 0; kk < Hdim / 4; ++kk) {
            float4 wv = w4[kk];
            float4 hv = h4[kk];
            s += wv.x * hv.x + wv.y * hv.y + wv.z * hv.z + wv.w * hv.w;
        }
        zbuf[b * 32 + n] = fmaxf(s, 0.0f);
    }
    __syncthreads();
    if (tid < ROWS) {
        float s = b2[0];
        #pragma unroll
        for (int n = 0; n < 32; ++n) s += zbuf[tid * 32 + n] * W2[n];
        float e = fast_exp2(-LOG2E * s);
        out[b0 + tid] = fast_rcp(1.0f + e);
    }
}

extern "C" void kernel_launch(void* const* d_in, const int* in_sizes, int n_in,
                              void* d_out, int out_size, void* d_ws, size_t ws_size,
                              hipStream_t stream) {
    const float* x    = (const float*)d_in[0];
    const float* W_ih = (const float*)d_in[1];
    const float* W_hh = (const float*)d_in[2];
    const float* b_ih = (const float*)d_in[3];
    const float* b_hh = (const float*)d_in[4];
    const float* W1   = (const float*)d_in[5];
    const float* b1   = (const float*)d_in[6];
    const float* W2   = (const float*)d_in[7];
    const float* b2   = (const float*)d_in[8];
    float* out = (float*)d_out;

    dim3 grid(Bsz / ROWS), block(NTH);
    lstm_fused<<<grid, block, 0, stream>>>(x, W_ih, W_hh, b_ih, b_hh, W1, b1, W2, b2, out);
}

// Round 8
// 343.367 us; speedup vs baseline: 1.2161x; 1.1595x over previous
//
#include <hip/hip_runtime.h>

// Round 15: r9 RESTORED (223.5us, session best) + three zero-risk trims
// salvaged from failed structural rounds (each proven correct there):
//  (1) prescale: W,bias scaled by -log2e (i,f,o) / -2log2e (g) at load
//      (r11/r13-proven). Cellmath exp2 consumes acc directly: -4 v_mul/cell.
//  (2) balanced staging: ALL 512 threads write ONE dup copy (tid>>8 picks
//      row vs row+8) instead of waves 0-3 writing two -> halves per-thread
//      staging work, removes barrier-arrival skew between wave groups.
//  (3) x-frag ds_reads issued before h-frags: x-MFMA operands don't queue
//      behind the 4 hf reads in the lgkm chain.
// Model (fits r8-r14): step 2095cyc/SIMD = MFMA 931 (half = forced M=16 dup
// waste) + VALU ~900 (7-trans cellmath = LSTM minimum) + ds ~120 + barrier
// ~150 + writes, near-serialized by lockstep waves. Six structural
// alternatives (r10-r14) all regressed; this is r9 + trims only.

#define Bsz   2048
#define Tlen  256
#define Fdim  64
#define Hdim  128
#define ROWS  8
#define NTH   512
#define TILE_E 512            // elems per kt tile (64 lanes x 8)
#define NKT   6               // kt 0,1 = x (K 0..63), kt 2..5 = h (K 64..191)
#define BUF_E (NKT * TILE_E)  // 3072 bf16 = 6 KB per buffer

using bf16x8 = __attribute__((ext_vector_type(8))) __bf16;
using f32x4  = __attribute__((ext_vector_type(4))) float;

__device__ __forceinline__ float fast_rcp(float x) {
#if __has_builtin(__builtin_amdgcn_rcpf)
    return __builtin_amdgcn_rcpf(x);
#else
    return 1.0f / x;
#endif
}
__device__ __forceinline__ float fast_exp2(float x) {
#if __has_builtin(__builtin_amdgcn_exp2f)
    return __builtin_amdgcn_exp2f(x);
#else
    return exp2f(x);
#endif
}
#define LOG2E  1.4426950408889634f
#define LOG2E2 2.8853900817779268f

__device__ __forceinline__ bf16x8 cvt8s(float4 a, float4 b, float s) {
    bf16x8 r;
    r[0]=(__bf16)(s*a.x); r[1]=(__bf16)(s*a.y); r[2]=(__bf16)(s*a.z); r[3]=(__bf16)(s*a.w);
    r[4]=(__bf16)(s*b.x); r[5]=(__bf16)(s*b.y); r[6]=(__bf16)(s*b.z); r[7]=(__bf16)(s*b.w);
    return r;
}

// frag-order elem index for logical A[frag_row][k]
__device__ __forceinline__ int frag_elem(int row, int k) {
    return (k >> 5) * TILE_E + ((((k >> 3) & 3) * 16 + row) * 8) + (k & 7);
}

__global__ __launch_bounds__(NTH, 2)
void lstm_fused(const float* __restrict__ x,
                const float* __restrict__ W_ih,
                const float* __restrict__ W_hh,
                const float* __restrict__ b_ih,
                const float* __restrict__ b_hh,
                const float* __restrict__ W1,
                const float* __restrict__ b1,
                const float* __restrict__ W2,
                const float* __restrict__ b2,
                float* __restrict__ out)
{
    __shared__ __bf16 Abuf[2][BUF_E];       // 12 KB, fragment-order A operand
    __shared__ float  hlast[ROWS * Hdim];   // 4 KB fp32 h_T for head
    __shared__ float  zbuf[ROWS * 32];

    const int tid  = threadIdx.x;
    const int w    = tid >> 6;
    const int lane = tid & 63;
    const int quad = lane >> 4;
    const int l16  = lane & 15;
    const int b0   = blockIdx.x * ROWS;
    const bool hiq = (quad >= 2);           // selects acc elems {2,3} vs {0,1}

    // ---- weights, register-resident, PRESCALED (trim 1) ----
    // lane holds B[k = kt*32 + quad*8 + j][n = g*128 + w*16 + l16]
    // scale: i,f,o -> -log2e ; g -> -2log2e  => exp2(acc) = e^{-z} / e^{-2z}
    bf16x8 bwx[2][4], bwh[4][4];
    #pragma unroll
    for (int kt = 0; kt < NKT; ++kt) {
        const int k0 = kt * 32 + quad * 8;
        #pragma unroll
        for (int g = 0; g < 4; ++g) {
            const float s = (g == 2) ? -LOG2E2 : -LOG2E;
            const int n = g * Hdim + w * 16 + l16;
            const float* p = (kt < 2) ? (W_ih + (size_t)n * Fdim + k0)
                                      : (W_hh + (size_t)n * Hdim + (k0 - Fdim));
            float4 lo = *(const float4*)p;
            float4 hi = *(const float4*)(p + 4);
            bf16x8 r = cvt8s(lo, hi, s);
            if (kt < 2) bwx[kt][g] = r; else bwh[kt - 2][g] = r;
        }
    }
    // bias pre-splatted (prescaled); used directly as MFMA C-in
    f32x4 biasf[4];
    #pragma unroll
    for (int g = 0; g < 4; ++g) {
        const float s = (g == 2) ? -LOG2E2 : -LOG2E;
        const int n = g * Hdim + w * 16 + l16;
        const float bv = s * (b_ih[n] + b_hh[n]);
        biasf[g] = (f32x4){bv, bv, bv, bv};
    }

    // ---- x staging (trim 2): ALL 512 threads, ONE uint write each ----
    // thread -> (row = tid&7, feat pair, half): half 0 writes frag row,
    // half 1 writes frag row+8 (the dup copy). Same x value both halves
    // (same address -> L1 broadcast, no extra HBM).
    const int  sx_row  = tid & 7;
    const int  sx_fp   = (tid >> 3) & 31;
    const int  sx_half = (tid >> 8) & 1;
    const int  f0      = 2 * sx_fp;
    const float* xrp   = x + (size_t)(b0 + sx_row) * (Tlen * Fdim) + f0;
    const int  sx_e    = frag_elem(sx_row + 8 * sx_half, f0);

    // ---- elementwise cells (r5 mapping): 2 real cells/lane ----
    const int r0  = (quad >> 1) * 2;
    const int brb = (quad & 1) * 4 + r0;     // batch rows brb, brb+1
    const int hc  = 16 * w + l16;            // H-col 0..127
    const int h_e0a = frag_elem(brb,         Fdim + hc);
    const int h_e0b = frag_elem(brb + 8,     Fdim + hc);
    const int h_e1a = frag_elem(brb + 1,     Fdim + hc);
    const int h_e1b = frag_elem(brb + 1 + 8, Fdim + hc);

    // ---- init: zero buf0 (h0 = 0), stage x(1)->buf0, prefetch x(2),x(3) ----
    #pragma unroll
    for (int i = 0; i < BUF_E / NTH; ++i)
        Abuf[0][tid + i * NTH] = (__bf16)0.0f;
    __syncthreads();
    float2 xpA, xpB;                         // staged at even / odd t
    {
        float2 v1 = *(const float2*)(xrp + Fdim);     // x(1) -> buf0 x-slots
        __bf16 a1[2] = {(__bf16)v1.x, (__bf16)v1.y};
        *(uint*)&Abuf[0][sx_e] = *(uint*)a1;
        xpA = *(const float2*)(xrp + 2 * Fdim);       // x(2), staged at t=0
        xpB = *(const float2*)(xrp + 3 * Fdim);       // x(3), staged at t=1
    }
    // xacc(0) = biasf + x(0) W_ih^T (prescaled), direct global fragment load
    f32x4 xacc[4];
    {
        const float* x0p = x + (size_t)(b0 + (l16 & 7)) * (Tlen * Fdim) + quad * 8;
        float4 a0 = *(const float4*)(x0p);
        float4 a1 = *(const float4*)(x0p + 4);
        float4 a2 = *(const float4*)(x0p + 32);
        float4 a3 = *(const float4*)(x0p + 36);
        bf16x8 xi0 = cvt8s(a0, a1, 1.0f), xi1 = cvt8s(a2, a3, 1.0f);
        #pragma unroll
        for (int g = 0; g < 4; ++g) {
            f32x4 tmp = __builtin_amdgcn_mfma_f32_16x16x32_bf16(xi0, bwx[0][g], biasf[g], 0, 0, 0);
            xacc[g]   = __builtin_amdgcn_mfma_f32_16x16x32_bf16(xi1, bwx[1][g], tmp, 0, 0, 0);
        }
    }
    __syncthreads();

    float cc0 = 0.0f, cc1 = 0.0f;

    // One step. Program order: [2x ds_read (xf, trim 3) | 4x ds_read (hf) |
    // prefetch issue | 16 h-MFMA | 8 x-MFMA | staging write | SB(0) |
    // cellmath | h-writes | lgkmcnt | s_barrier]
    auto step = [&](int t, const __bf16* __restrict__ rb,
                    __bf16* __restrict__ wbf, float2& xstage) {
        // x(t+1) fragments first (trim 3)
        bf16x8 xf0 = *(const bf16x8*)&rb[lane * 8];
        bf16x8 xf1 = *(const bf16x8*)&rb[TILE_E + lane * 8];
        // h(t-1) fragments: 4x conflict-free ds_read_b128 at lane*16B
        bf16x8 hf[4];
        #pragma unroll
        for (int kt = 0; kt < 4; ++kt)
            hf[kt] = *(const bf16x8*)&rb[(2 + kt) * TILE_E + lane * 8];

        // grab completed x(t+2), issue x(t+4) prefetch (rides the barriers
        // on vmcnt -- never drained in-loop)
        float2 xcur = xstage;
        if ((t + 4) < Tlen)
            xstage = *(const float2*)(xrp + (size_t)(t + 4) * Fdim);

        // gates(t) = xacc(t) + h-part: 16 MFMAs, xacc folded in as C-in
        f32x4 acc[4];
        #pragma unroll
        for (int g = 0; g < 4; ++g)
            acc[g] = __builtin_amdgcn_mfma_f32_16x16x32_bf16(hf[0], bwh[0][g], xacc[g], 0, 0, 0);
        #pragma unroll
        for (int kt = 1; kt < 4; ++kt) {
            #pragma unroll
            for (int g = 0; g < 4; ++g)
                acc[g] = __builtin_amdgcn_mfma_f32_16x16x32_bf16(hf[kt], bwh[kt][g], acc[g], 0, 0, 0);
        }

        // xacc(t+1) = biasf + x(t+1) W_ih^T -- MFMA pipe drains these under
        // the elementwise VALU phase (hides the h-MFMA latency tail too)
        if ((t + 1) < Tlen) {
            #pragma unroll
            for (int g = 0; g < 4; ++g) {
                f32x4 tmp = __builtin_amdgcn_mfma_f32_16x16x32_bf16(xf0, bwx[0][g], biasf[g], 0, 0, 0);
                xacc[g]   = __builtin_amdgcn_mfma_f32_16x16x32_bf16(xf1, bwx[1][g], tmp, 0, 0, 0);
            }
        }

        // stage x(t+2): one uint per thread (trim 2)
        if ((t + 2) < Tlen) {
            __bf16 xa[2] = {(__bf16)xcur.x, (__bf16)xcur.y};
            *(uint*)&wbf[sx_e] = *(uint*)xa;
        }

        // pin: all memory + MFMA issue above the elementwise phase
        __builtin_amdgcn_sched_barrier(0);

        // elementwise: 2 cells/lane, rcp-fused, prescaled (exp2 direct)
        {
            float ei = fast_exp2(hiq ? acc[0][2] : acc[0][0]);
            float ef = fast_exp2(hiq ? acc[1][2] : acc[1][0]);
            float eg = fast_exp2(hiq ? acc[2][2] : acc[2][0]);
            float eo = fast_exp2(hiq ? acc[3][2] : acc[3][0]);
            float a = 1.0f + ef, b = 1.0f + ei, d = 1.0f + eg;
            float bd  = b * d;
            float num = cc0 * bd + a * (1.0f - eg);
            cc0 = num * fast_rcp(a * bd);
            float ec = fast_exp2(-LOG2E2 * cc0);
            float h  = (1.0f - ec) * fast_rcp((1.0f + eo) * (1.0f + ec));
            __bf16 hb = (__bf16)h;
            wbf[h_e0a] = hb;
            wbf[h_e0b] = hb;
            if (t == Tlen - 1) hlast[brb * Hdim + hc] = h;
        }
        {
            float ei = fast_exp2(hiq ? acc[0][3] : acc[0][1]);
            float ef = fast_exp2(hiq ? acc[1][3] : acc[1][1]);
            float eg = fast_exp2(hiq ? acc[2][3] : acc[2][1]);
            float eo = fast_exp2(hiq ? acc[3][3] : acc[3][1]);
            float a = 1.0f + ef, b = 1.0f + ei, d = 1.0f + eg;
            float bd  = b * d;
            float num = cc1 * bd + a * (1.0f - eg);
            cc1 = num * fast_rcp(a * bd);
            float ec = fast_exp2(-LOG2E2 * cc1);
            float h  = (1.0f - ec) * fast_rcp((1.0f + eo) * (1.0f + ec));
            __bf16 hb = (__bf16)h;
            wbf[h_e1a] = hb;
            wbf[h_e1b] = hb;
            if (t == Tlen - 1) hlast[(brb + 1) * Hdim + hc] = h;
        }

        // non-draining barrier: LDS visible (lgkmcnt 0); global prefetch
        // stays in flight (NO vmcnt drain -- the r8 win, preserved).
        asm volatile("s_waitcnt lgkmcnt(0)" ::: "memory");
        __builtin_amdgcn_s_barrier();
        __builtin_amdgcn_sched_barrier(0);
    };

    for (int t = 0; t < Tlen; t += 2) {
        step(t,     Abuf[0], Abuf[1], xpA);
        step(t + 1, Abuf[1], Abuf[0], xpB);
    }

    // ---- head: z = relu(h @ W1^T + b1); out = sigmoid(z @ W2^T + b2) ----
    // (final loop barrier drained lgkmcnt and synced all waves: hlast safe)
    if (tid < ROWS * 32) {
        const int b = tid >> 5, n = tid & 31;
        const float4* w4 = (const float4*)(W1 + n * Hdim);
        const float4* h4 = (const float4*)(hlast + b * Hdim);
        float s = b1[n];
        #pragma unroll
        for (int kk = 0; kk < Hdim / 4; ++kk) {
            float4 wv = w4[kk];
            float4 hv = h4[kk];
            s += wv.x * hv.x + wv.y * hv.y + wv.z * hv.z + wv.w * hv.w;
        }
        zbuf[b * 32 + n] = fmaxf(s, 0.0f);
    }
    __syncthreads();
    if (tid < ROWS) {
        float s = b2[0];
        #pragma unroll
        for (int n = 0; n < 32; ++n) s += zbuf[tid * 32 + n] * W2[n];
        float e = fast_exp2(-LOG2E * s);
        out[b0 + tid] = fast_rcp(1.0f + e);
    }
}

extern "C" void kernel_launch(void* const* d_in, const int* in_sizes, int n_in,
                              void* d_out, int out_size, void* d_ws, size_t ws_size,
                              hipStream_t stream) {
    const float* x    = (const float*)d_in[0];
    const float* W_ih = (const float*)d_in[1];
    const float* W_hh = (const float*)d_in[2];
    const float* b_ih = (const float*)d_in[3];
    const float* b_hh = (const float*)d_in[4];
    const float* W1   = (const float*)d_in[5];
    const float* b1   = (const float*)d_in[6];
    const float* W2   = (const float*)d_in[7];
    const float* b2   = (const float*)d_in[8];
    float* out = (float*)d_out;

    dim3 grid(Bsz / ROWS), block(NTH);
    lstm_fused<<<grid, block, 0, stream>>>(x, W_ih, W_hh, b_ih, b_hh, W1, b1, W2, b2, out);
}